// Round 5
// baseline (2618.860 us; speedup 1.0000x reference)
//
#include <hip/hip_runtime.h>
#include <math.h>

typedef unsigned short u16;
typedef unsigned int u32;

using short8 = __attribute__((ext_vector_type(8))) short;
using f32x4  = __attribute__((ext_vector_type(4))) float;
typedef _Float16 h2_t __attribute__((ext_vector_type(2)));
using half8  = __attribute__((ext_vector_type(8))) _Float16;

typedef const __attribute__((address_space(1))) unsigned int* gas_ptr;
typedef __attribute__((address_space(3))) unsigned int* las_ptr;

__device__ __forceinline__ void load_lds16(const void* g, void* l) {
    __builtin_amdgcn_global_load_lds((gas_ptr)g, (las_ptr)l, 16, 0, 0);
}

__device__ __forceinline__ u16 bf16b(float f) {
    u32 u = __builtin_bit_cast(u32, f);
    u += 0x7fffu + ((u >> 16) & 1u);
    return (u16)(u >> 16);
}
__device__ __forceinline__ float b2f(u16 h) {
    u32 u = (u32)h << 16;
    return __builtin_bit_cast(float, u);
}

__device__ __forceinline__ float tanhf_fast(float z) {
    float e = __expf(2.0f * z);                       // inf for big z -> h=1; 0 -> h=-1
    return 1.0f - 2.0f * __builtin_amdgcn_rcpf(e + 1.0f);
}

// ---------------------------------------------------------------- fp32 -> bf16 (contig)
__global__ void cvt_kernel(const float4* __restrict__ s, ushort4* __restrict__ d, int n4) {
    for (int i = blockIdx.x * blockDim.x + threadIdx.x; i < n4; i += gridDim.x * blockDim.x) {
        float4 v = s[i];
        ushort4 o;
        o.x = bf16b(v.x); o.y = bf16b(v.y); o.z = bf16b(v.z); o.w = bf16b(v.w);
        d[i] = o;
    }
}
// fp32 [R,K] -> bf16 or f16 into dst[r*stride + col0 + k]
template<bool F16>
__global__ void cvt_str_kernel(const float4* __restrict__ s, u16* __restrict__ d,
                               int K4, int n4, int stride, int col0) {
    for (int i = blockIdx.x * blockDim.x + threadIdx.x; i < n4; i += gridDim.x * blockDim.x) {
        float4 v = s[i];
        int r = i / K4, k4 = (i - r * K4) * 4;
        ushort4 o;
        if (F16) {
            o.x = __builtin_bit_cast(u16, (_Float16)v.x);
            o.y = __builtin_bit_cast(u16, (_Float16)v.y);
            o.z = __builtin_bit_cast(u16, (_Float16)v.z);
            o.w = __builtin_bit_cast(u16, (_Float16)v.w);
        } else {
            o.x = bf16b(v.x); o.y = bf16b(v.y); o.z = bf16b(v.z); o.w = bf16b(v.w);
        }
        *(ushort4*)(d + (size_t)r * stride + col0 + k4) = o;
    }
}

// ---------------------------------------------------------------- generic GEMM
// C[M,N] = A[M,K] * B^T, B is [N,K] row-major. 128x128 tile, BK=64, 256 thr.
// MODE 0: out16[row*os+col] = f16(acc)                                (G1: xB, f16 out)
// MODE 1: split-A (st f16 K=256 | x bf16 K=1024); kt<4 uses f16 MFMA.
//         out16 = bf16(acc + addf[row*1024+col])                      (G2: pre-LN)
// MODE 2: out16[row*os+col] = bf16(gelu(acc + bias[col]))             (G3: FFN1)
// MODE 3: out32[row*1024+col] = acc + bias[col] + b2f(add16[row*1024+col])  (G4)
template<int MODE>
__global__ __launch_bounds__(256) void gemm_bf16(
    const u16* __restrict__ Ab, const u16* __restrict__ Ab2, const u16* __restrict__ Bb,
    int K, int ktiles,
    float* __restrict__ out32, u16* __restrict__ out16,
    const float* __restrict__ bias, const float* __restrict__ addf,
    const u16* __restrict__ add16, int out_stride)
{
    __shared__ __align__(16) u16 Als[128 * 64];
    __shared__ __align__(16) u16 Bls[128 * 64];

    const int tid  = threadIdx.x;
    const int lane = tid & 63;
    const int w    = tid >> 6;
    const int wr   = (w >> 1) * 64;
    const int wc   = (w & 1) * 64;
    const int fr   = lane & 15;
    const int fkB  = (lane >> 4) * 16;

    const size_t rbB = (size_t)K * 2;
    const int arow = blockIdx.y * 128 + (tid >> 3);
    const char* Ag  = (const char*)Ab + (size_t)arow * ((MODE == 1) ? 512 : rbB) + (size_t)(tid & 7) * 16;
    const char* Ag2 = (MODE == 1) ? ((const char*)Ab2 + (size_t)arow * 2048 + (size_t)(tid & 7) * 16) : nullptr;
    const char* Bg  = (const char*)Bb + ((size_t)blockIdx.x * 128 + (tid >> 3)) * rbB + (size_t)(tid & 7) * 16;
    char* Ald = (char*)Als + tid * 16;
    char* Bld = (char*)Bls + tid * 16;

    f32x4 acc[4][4];
#pragma unroll
    for (int m = 0; m < 4; ++m)
#pragma unroll
        for (int n = 0; n < 4; ++n)
            acc[m][n] = f32x4{0.f, 0.f, 0.f, 0.f};

    for (int kt = 0; kt < ktiles; ++kt) {
        __syncthreads();
        const char* Asrc;
        size_t rbA;
        if (MODE == 1) {
            if (kt < 4) { Asrc = Ag  + (size_t)kt * 128;       rbA = 512;  }
            else        { Asrc = Ag2 + (size_t)(kt - 4) * 128; rbA = 2048; }
        } else {
            Asrc = Ag + (size_t)kt * 128; rbA = rbB;
        }
        const char* Bsrc = Bg + (size_t)kt * 128;
#pragma unroll
        for (int i = 0; i < 4; ++i) {
            load_lds16(Asrc + (size_t)(i * 32) * rbA, Ald + i * 4096);
            load_lds16(Bsrc + (size_t)(i * 32) * rbB, Bld + i * 4096);
        }
        __syncthreads();
        const bool f16t = (MODE == 1) && (kt < 4);
#pragma unroll
        for (int kk = 0; kk < 2; ++kk) {
            short8 af[4], bfr[4];
#pragma unroll
            for (int m = 0; m < 4; ++m)
                af[m] = *(const short8*)((const char*)Als + (wr + m * 16 + fr) * 128 + kk * 64 + fkB);
#pragma unroll
            for (int n = 0; n < 4; ++n)
                bfr[n] = *(const short8*)((const char*)Bls + (wc + n * 16 + fr) * 128 + kk * 64 + fkB);
            if (f16t) {
#pragma unroll
                for (int m = 0; m < 4; ++m)
#pragma unroll
                    for (int n = 0; n < 4; ++n)
                        acc[m][n] = __builtin_amdgcn_mfma_f32_16x16x32_f16(
                            __builtin_bit_cast(half8, af[m]), __builtin_bit_cast(half8, bfr[n]),
                            acc[m][n], 0, 0, 0);
            } else {
#pragma unroll
                for (int m = 0; m < 4; ++m)
#pragma unroll
                    for (int n = 0; n < 4; ++n)
                        acc[m][n] = __builtin_amdgcn_mfma_f32_16x16x32_bf16(af[m], bfr[n], acc[m][n], 0, 0, 0);
            }
        }
    }

    const int rbase = blockIdx.y * 128 + wr + (lane >> 4) * 4;
    const int cbase = blockIdx.x * 128 + wc + fr;
#pragma unroll
    for (int m = 0; m < 4; ++m) {
#pragma unroll
        for (int n = 0; n < 4; ++n) {
            const int col = cbase + n * 16;
#pragma unroll
            for (int r = 0; r < 4; ++r) {
                const int row = rbase + m * 16 + r;
                float v = acc[m][n][r];
                if (MODE == 0) {
                    out16[(size_t)row * out_stride + col] = __builtin_bit_cast(u16, (_Float16)v);
                } else if (MODE == 1) {
                    out16[(size_t)row * 1024 + col] = bf16b(v + addf[(size_t)row * 1024 + col]);
                } else if (MODE == 2) {
                    float u = v + bias[col];
                    u = 0.5f * u * (1.0f + erff(u * 0.70710678118654752f));
                    out16[(size_t)row * out_stride + col] = bf16b(u);
                } else {
                    out32[(size_t)row * 1024 + col] =
                        v + bias[col] + b2f(add16[(size_t)row * 1024 + col]);
                }
            }
        }
    }
}

// ---------------------------------------------------------------- MFMA scan
// ONE block, 256 threads (4 waves). All 8 batches as MFMA output-cols (16 with pad).
// Wave w owns output rows n in [64w, 64w+64) as 4 tiles; A[256][256] f16 lives in
// registers (af[4][8], 128 VGPR). State (f16) double-buffered in LDS in frag layout:
//   SB[p][kk*1024 + l*16 + j*2] = S[b = l&15][n = kk*32 + (l>>4)*8 + j]
// Per step: 8 ds_read_b128 + 32 mfma_f16 + tanh + 4 ds_write_b64 + 1 barrier.
__global__ __launch_bounds__(256) void scan_mfma_kernel(
    const float* __restrict__ Am, const u16* __restrict__ xBh /*f16 [8][2048][256]*/,
    u16* __restrict__ sth /*f16 [8][2048][256]*/, float* __restrict__ fstate)
{
    __shared__ __align__(16) char SB[2][8192];
    const int tid = threadIdx.x;
    const int l = tid & 63, w = tid >> 6;
    const int b = l & 15, g = l >> 4;
    const int bc = b < 8 ? b : 7;
    const bool breal = (b < 8);

    // A fragments: af[nt][kk], lane holds A[64w+nt*16+(l&15)][kk*32+(l>>4)*8 + j]
    half8 af[4][8];
#pragma unroll
    for (int nt = 0; nt < 4; ++nt)
#pragma unroll
        for (int kk = 0; kk < 8; ++kk) {
            const float* ap = Am + (size_t)(64 * w + nt * 16 + b) * 256 + kk * 32 + g * 8;
            float4 f0 = *(const float4*)ap;
            float4 f1 = *(const float4*)(ap + 4);
            half8 h;
            h[0] = (_Float16)f0.x; h[1] = (_Float16)f0.y; h[2] = (_Float16)f0.z; h[3] = (_Float16)f0.w;
            h[4] = (_Float16)f1.x; h[5] = (_Float16)f1.y; h[6] = (_Float16)f1.z; h[7] = (_Float16)f1.w;
            af[nt][kk] = h;
        }

    {   // zero both state buffers (16 KiB)
        uint4 z = uint4{0u, 0u, 0u, 0u};
#pragma unroll
        for (int i = 0; i < 4; ++i)
            ((uint4*)SB)[tid + 256 * i] = z;
    }

    // per-lane constants: output rows n0[nt] = 64w + nt*16 + g*4 (+r), write offsets
    int n0[4], wb[4];
    const u16* xp[4];
    u16* sp[4];
#pragma unroll
    for (int nt = 0; nt < 4; ++nt) {
        int n = 64 * w + nt * 16 + g * 4;
        n0[nt] = n;
        wb[nt] = (n >> 5) * 1024 + (b + 16 * ((n & 31) >> 3)) * 16 + (n & 7) * 2;
        xp[nt] = xBh + (size_t)bc * 2048 * 256 + n;
        sp[nt] = sth + (size_t)bc * 2048 * 256 + n;
    }

    uint2 xc0, xc1, xc2, xc3, xn0, xn1, xn2, xn3;
    xc0 = *(const uint2*)(xp[0]); xp[0] += 256;
    xc1 = *(const uint2*)(xp[1]); xp[1] += 256;
    xc2 = *(const uint2*)(xp[2]); xp[2] += 256;
    xc3 = *(const uint2*)(xp[3]); xp[3] += 256;
    xn0 = xc0; xn1 = xc1; xn2 = xc2; xn3 = xc3;
    __syncthreads();

#define UNPK(XC) f32x4{ (float)__builtin_bit_cast(h2_t, (XC).x)[0],            \
                        (float)__builtin_bit_cast(h2_t, (XC).x)[1],            \
                        (float)__builtin_bit_cast(h2_t, (XC).y)[0],            \
                        (float)__builtin_bit_cast(h2_t, (XC).y)[1] }

#define MM(KK)                                                                 \
    acc0 = __builtin_amdgcn_mfma_f32_16x16x32_f16(af[0][KK], __builtin_bit_cast(half8, s##KK), acc0, 0, 0, 0); \
    acc1 = __builtin_amdgcn_mfma_f32_16x16x32_f16(af[1][KK], __builtin_bit_cast(half8, s##KK), acc1, 0, 0, 0); \
    acc2 = __builtin_amdgcn_mfma_f32_16x16x32_f16(af[2][KK], __builtin_bit_cast(half8, s##KK), acc2, 0, 0, 0); \
    acc3 = __builtin_amdgcn_mfma_f32_16x16x32_f16(af[3][KK], __builtin_bit_cast(half8, s##KK), acc3, 0, 0, 0);

#define FIN(NT, ACC, T, PW)                                                    \
    {                                                                          \
        float h0 = tanhf_fast((ACC)[0]);                                       \
        float h1 = tanhf_fast((ACC)[1]);                                       \
        float h2 = tanhf_fast((ACC)[2]);                                       \
        float h3 = tanhf_fast((ACC)[3]);                                       \
        h2_t pa{(_Float16)h0, (_Float16)h1};                                   \
        h2_t pb{(_Float16)h2, (_Float16)h3};                                   \
        uint2 pk;                                                              \
        pk.x = __builtin_bit_cast(u32, pa);                                    \
        pk.y = __builtin_bit_cast(u32, pb);                                    \
        *(uint2*)(&SB[PW][0] + wb[NT]) = pk;                                   \
        if (breal) *(uint2*)(sp[NT]) = pk;                                     \
        sp[NT] += 256;                                                         \
        if ((T) == 2047 && breal)                                              \
            *(float4*)(fstate + b * 256 + n0[NT]) = float4{h0, h1, h2, h3};    \
    }

#define STEP(T, PR, PW, XC0, XC1, XC2, XC3, XN0, XN1, XN2, XN3)                \
    {                                                                          \
        const char* rb = &SB[PR][0] + l * 16;                                  \
        uint4 s0 = *(const uint4*)(rb + 0 * 1024);                             \
        uint4 s1 = *(const uint4*)(rb + 1 * 1024);                             \
        uint4 s2 = *(const uint4*)(rb + 2 * 1024);                             \
        uint4 s3 = *(const uint4*)(rb + 3 * 1024);                             \
        uint4 s4 = *(const uint4*)(rb + 4 * 1024);                             \
        uint4 s5 = *(const uint4*)(rb + 5 * 1024);                             \
        uint4 s6 = *(const uint4*)(rb + 6 * 1024);                             \
        uint4 s7 = *(const uint4*)(rb + 7 * 1024);                             \
        XN0 = *(const uint2*)(xp[0]); xp[0] += 256;                            \
        XN1 = *(const uint2*)(xp[1]); xp[1] += 256;                            \
        XN2 = *(const uint2*)(xp[2]); xp[2] += 256;                            \
        XN3 = *(const uint2*)(xp[3]); xp[3] += 256;                            \
        f32x4 acc0 = UNPK(XC0), acc1 = UNPK(XC1), acc2 = UNPK(XC2), acc3 = UNPK(XC3); \
        MM(0) MM(1) MM(2) MM(3) MM(4) MM(5) MM(6) MM(7)                        \
        FIN(0, acc0, T, PW) FIN(1, acc1, T, PW)                                \
        FIN(2, acc2, T, PW) FIN(3, acc3, T, PW)                                \
        asm volatile("s_waitcnt lgkmcnt(0)\n\ts_barrier" ::: "memory");        \
    }

    for (int t = 0; t < 2048; t += 2) {
        STEP(t,     0, 1, xc0, xc1, xc2, xc3, xn0, xn1, xn2, xn3);
        STEP(t + 1, 1, 0, xn0, xn1, xn2, xn3, xc0, xc1, xc2, xc3);
    }
#undef STEP
#undef FIN
#undef MM
#undef UNPK
}

// ---------------------------------------------------------------- layernorm (row per block, bf16 in)
__global__ __launch_bounds__(256) void ln_kernel(
    const u16* __restrict__ pre /*bf16, stride 1024*/, const float* __restrict__ gam,
    const float* __restrict__ bet, u16* __restrict__ ybf)
{
    const int row = blockIdx.x, tid = threadIdx.x;
    const ushort4 pv = *(const ushort4*)(pre + (size_t)row * 1024 + tid * 4);
    float vx = b2f(pv.x), vy = b2f(pv.y), vz = b2f(pv.z), vw = b2f(pv.w);
    float sum = vx + vy + vz + vw;
    float sq  = vx * vx + vy * vy + vz * vz + vw * vw;
#pragma unroll
    for (int o = 32; o; o >>= 1) { sum += __shfl_xor(sum, o); sq += __shfl_xor(sq, o); }
    __shared__ float red[8];
    const int lane = tid & 63, wv = tid >> 6;
    if (!lane) { red[wv] = sum; red[4 + wv] = sq; }
    __syncthreads();
    sum = red[0] + red[1] + red[2] + red[3];
    sq  = red[4] + red[5] + red[6] + red[7];
    const float mu  = sum * (1.f / 1024.f);
    const float var = sq * (1.f / 1024.f) - mu * mu;
    const float rs  = rsqrtf(var + 1e-5f);
    const float4 g  = *(const float4*)(gam + tid * 4);
    const float4 be = *(const float4*)(bet + tid * 4);
    ushort4 ob;
    ob.x = bf16b((vx - mu) * rs * g.x + be.x);
    ob.y = bf16b((vy - mu) * rs * g.y + be.y);
    ob.z = bf16b((vz - mu) * rs * g.z + be.z);
    ob.w = bf16b((vw - mu) * rs * g.w + be.w);
    *(ushort4*)(ybf + (size_t)row * 1024 + tid * 4) = ob;
}

// ---------------------------------------------------------------- launch
extern "C" void kernel_launch(void* const* d_in, const int* in_sizes, int n_in,
                              void* d_out, int out_size, void* d_ws, size_t ws_size,
                              hipStream_t stream)
{
    const float* x    = (const float*)d_in[0];
    const float* A    = (const float*)d_in[1];
    const float* Bm   = (const float*)d_in[2];
    const float* C    = (const float*)d_in[3];
    const float* D    = (const float*)d_in[4];
    const float* ln_w = (const float*)d_in[5];
    const float* ln_b = (const float*)d_in[6];
    const float* W1   = (const float*)d_in[7];
    const float* b1   = (const float*)d_in[8];
    const float* W2   = (const float*)d_in[9];
    const float* b2   = (const float*)d_in[10];

    // workspace layout (total 135,790,592 B)
    char* ws = (char*)d_ws;
    u16* Bm_bf  = (u16*)(ws + 0);            //    524,288 B [256 x 1024] bf16
    u16* CD_bf  = (u16*)(ws + 524288);       //  2,621,440 B [1024 x 1280] = C(f16)|D(bf16)
    u16* W1b    = (u16*)(ws + 3145728);      //  8,388,608 B bf16
    u16* W2b    = (u16*)(ws + 11534336);     //  8,388,608 B bf16
    u16* xB_h   = (u16*)(ws + 19922944);     //  8,388,608 B [8][2048][256] f16
    u16* st_h   = (u16*)(ws + 28311552);     //  8,388,608 B [8][2048][256] f16
    u16* y_bf   = (u16*)(ws + 36700160);     // 33,554,432 B [16384 x 1024] bf16
    u16* pre_bf = (u16*)(ws + 70254592);     // 33,554,432 B [16384 x 1024] bf16
    u16* xh_bf  = (u16*)(ws + 103809024);    // 33,554,432 B shared: x_bf / h_bf

    float* out = (float*)d_out;              // [16384*1024] y, then [2048] final_state

    cvt_kernel<<<2048, 256, 0, stream>>>((const float4*)x,  (ushort4*)xh_bf, 4194304);
    cvt_kernel<<<256,  256, 0, stream>>>((const float4*)Bm, (ushort4*)Bm_bf, 65536);
    cvt_str_kernel<true ><<<256,  256, 0, stream>>>((const float4*)C, CD_bf, 64, 65536, 1280, 0);
    cvt_str_kernel<false><<<1024, 256, 0, stream>>>((const float4*)D, CD_bf, 256, 262144, 1280, 256);
    cvt_kernel<<<2048, 256, 0, stream>>>((const float4*)W1, (ushort4*)W1b, 1048576);
    cvt_kernel<<<2048, 256, 0, stream>>>((const float4*)W2, (ushort4*)W2b, 1048576);

    dim3 blk(256);
    // G1: xB = x @ Bm^T -> f16 [16384,256]
    gemm_bf16<0><<<dim3(2, 128), blk, 0, stream>>>(xh_bf, nullptr, Bm_bf, 1024, 16,
        nullptr, xB_h, nullptr, nullptr, nullptr, 256);
    // MFMA scan -> st_h (f16) + final_state (fp32 tail of d_out)
    scan_mfma_kernel<<<1, 256, 0, stream>>>(A, xB_h, st_h, out + 16777216);
    // G2: [st(f16) | x(bf16)] @ [C(f16) | D(bf16)]^T + x -> pre_bf (K=1280)
    gemm_bf16<1><<<dim3(8, 128), blk, 0, stream>>>(st_h, xh_bf, CD_bf, 1280, 20,
        nullptr, pre_bf, nullptr, x, nullptr, 1024);
    // LN
    ln_kernel<<<16384, 256, 0, stream>>>(pre_bf, ln_w, ln_b, y_bf);
    // FFN in 4 row-chunks of 4096 (h reuses xh_bf; x_bf dead after G2)
    for (int c = 0; c < 4; ++c) {
        const u16* yc = y_bf + (size_t)c * 4096 * 1024;
        float* oc = out + (size_t)c * 4096 * 1024;
        gemm_bf16<2><<<dim3(32, 32), blk, 0, stream>>>(yc, nullptr, W1b, 1024, 16,
            nullptr, xh_bf, b1, nullptr, nullptr, 4096);
        gemm_bf16<3><<<dim3(8, 32), blk, 0, stream>>>(xh_bf, nullptr, W2b, 4096, 64,
            oc, nullptr, b2, nullptr, yc, 1024);
    }
}

// Round 6
// 2606.252 us; speedup vs baseline: 1.0048x; 1.0048x over previous
//
#include <hip/hip_runtime.h>
#include <math.h>

typedef unsigned short u16;
typedef unsigned int u32;

using short8 = __attribute__((ext_vector_type(8))) short;
using f32x4  = __attribute__((ext_vector_type(4))) float;
typedef _Float16 h2_t __attribute__((ext_vector_type(2)));
using half8  = __attribute__((ext_vector_type(8))) _Float16;

typedef const __attribute__((address_space(1))) unsigned int* gas_ptr;
typedef __attribute__((address_space(3))) unsigned int* las_ptr;

__device__ __forceinline__ void load_lds16(const void* g, void* l) {
    __builtin_amdgcn_global_load_lds((gas_ptr)g, (las_ptr)l, 16, 0, 0);
}

__device__ __forceinline__ u16 bf16b(float f) {
    u32 u = __builtin_bit_cast(u32, f);
    u += 0x7fffu + ((u >> 16) & 1u);
    return (u16)(u >> 16);
}
__device__ __forceinline__ float b2f(u16 h) {
    u32 u = (u32)h << 16;
    return __builtin_bit_cast(float, u);
}

// tanh via exp2 + rcp: 3 VALU + 2 trans. Saturates exactly for |z| large.
__device__ __forceinline__ float tanh_e(float z) {
    float e = __builtin_amdgcn_exp2f(z * 2.885390081777927f);   // e^(2z)
    return 1.0f - 2.0f * __builtin_amdgcn_rcpf(e + 1.0f);
}

// pure-VALU cross-lane: rotate within each 16-lane row by 8 (involution: l <-> l^8)
__device__ __forceinline__ u32 ror8_u32(u32 v) {
    return (u32)__builtin_amdgcn_update_dpp(0, (int)v, 0x128, 0xF, 0xF, true);
}
__device__ __forceinline__ float ror8_f32(float v) {
    return __builtin_bit_cast(float,
        __builtin_amdgcn_update_dpp(0, __builtin_bit_cast(int, v), 0x128, 0xF, 0xF, true));
}

// ---------------------------------------------------------------- fp32 -> bf16 (contig)
__global__ void cvt_kernel(const float4* __restrict__ s, ushort4* __restrict__ d, int n4) {
    for (int i = blockIdx.x * blockDim.x + threadIdx.x; i < n4; i += gridDim.x * blockDim.x) {
        float4 v = s[i];
        ushort4 o;
        o.x = bf16b(v.x); o.y = bf16b(v.y); o.z = bf16b(v.z); o.w = bf16b(v.w);
        d[i] = o;
    }
}
// fp32 [R,K] -> bf16 or f16 into dst[r*stride + col0 + k]
template<bool F16>
__global__ void cvt_str_kernel(const float4* __restrict__ s, u16* __restrict__ d,
                               int K4, int n4, int stride, int col0) {
    for (int i = blockIdx.x * blockDim.x + threadIdx.x; i < n4; i += gridDim.x * blockDim.x) {
        float4 v = s[i];
        int r = i / K4, k4 = (i - r * K4) * 4;
        ushort4 o;
        if (F16) {
            o.x = __builtin_bit_cast(u16, (_Float16)v.x);
            o.y = __builtin_bit_cast(u16, (_Float16)v.y);
            o.z = __builtin_bit_cast(u16, (_Float16)v.z);
            o.w = __builtin_bit_cast(u16, (_Float16)v.w);
        } else {
            o.x = bf16b(v.x); o.y = bf16b(v.y); o.z = bf16b(v.z); o.w = bf16b(v.w);
        }
        *(ushort4*)(d + (size_t)r * stride + col0 + k4) = o;
    }
}

// ---------------------------------------------------------------- generic GEMM
// C[M,N] = A[M,K] * B^T, B is [N,K] row-major. 128x128 tile, BK=64, 256 thr.
template<int MODE>
__global__ __launch_bounds__(256) void gemm_bf16(
    const u16* __restrict__ Ab, const u16* __restrict__ Ab2, const u16* __restrict__ Bb,
    int K, int ktiles,
    float* __restrict__ out32, u16* __restrict__ out16,
    const float* __restrict__ bias, const float* __restrict__ addf,
    const u16* __restrict__ add16, int out_stride)
{
    __shared__ __align__(16) u16 Als[128 * 64];
    __shared__ __align__(16) u16 Bls[128 * 64];

    const int tid  = threadIdx.x;
    const int lane = tid & 63;
    const int w    = tid >> 6;
    const int wr   = (w >> 1) * 64;
    const int wc   = (w & 1) * 64;
    const int fr   = lane & 15;
    const int fkB  = (lane >> 4) * 16;

    const size_t rbB = (size_t)K * 2;
    const int arow = blockIdx.y * 128 + (tid >> 3);
    const char* Ag  = (const char*)Ab + (size_t)arow * ((MODE == 1) ? 512 : rbB) + (size_t)(tid & 7) * 16;
    const char* Ag2 = (MODE == 1) ? ((const char*)Ab2 + (size_t)arow * 2048 + (size_t)(tid & 7) * 16) : nullptr;
    const char* Bg  = (const char*)Bb + ((size_t)blockIdx.x * 128 + (tid >> 3)) * rbB + (size_t)(tid & 7) * 16;
    char* Ald = (char*)Als + tid * 16;
    char* Bld = (char*)Bls + tid * 16;

    f32x4 acc[4][4];
#pragma unroll
    for (int m = 0; m < 4; ++m)
#pragma unroll
        for (int n = 0; n < 4; ++n)
            acc[m][n] = f32x4{0.f, 0.f, 0.f, 0.f};

    for (int kt = 0; kt < ktiles; ++kt) {
        __syncthreads();
        const char* Asrc;
        size_t rbA;
        if (MODE == 1) {
            if (kt < 4) { Asrc = Ag  + (size_t)kt * 128;       rbA = 512;  }
            else        { Asrc = Ag2 + (size_t)(kt - 4) * 128; rbA = 2048; }
        } else {
            Asrc = Ag + (size_t)kt * 128; rbA = rbB;
        }
        const char* Bsrc = Bg + (size_t)kt * 128;
#pragma unroll
        for (int i = 0; i < 4; ++i) {
            load_lds16(Asrc + (size_t)(i * 32) * rbA, Ald + i * 4096);
            load_lds16(Bsrc + (size_t)(i * 32) * rbB, Bld + i * 4096);
        }
        __syncthreads();
        const bool f16t = (MODE == 1) && (kt < 4);
#pragma unroll
        for (int kk = 0; kk < 2; ++kk) {
            short8 af[4], bfr[4];
#pragma unroll
            for (int m = 0; m < 4; ++m)
                af[m] = *(const short8*)((const char*)Als + (wr + m * 16 + fr) * 128 + kk * 64 + fkB);
#pragma unroll
            for (int n = 0; n < 4; ++n)
                bfr[n] = *(const short8*)((const char*)Bls + (wc + n * 16 + fr) * 128 + kk * 64 + fkB);
            if (f16t) {
#pragma unroll
                for (int m = 0; m < 4; ++m)
#pragma unroll
                    for (int n = 0; n < 4; ++n)
                        acc[m][n] = __builtin_amdgcn_mfma_f32_16x16x32_f16(
                            __builtin_bit_cast(half8, af[m]), __builtin_bit_cast(half8, bfr[n]),
                            acc[m][n], 0, 0, 0);
            } else {
#pragma unroll
                for (int m = 0; m < 4; ++m)
#pragma unroll
                    for (int n = 0; n < 4; ++n)
                        acc[m][n] = __builtin_amdgcn_mfma_f32_16x16x32_bf16(af[m], bfr[n], acc[m][n], 0, 0, 0);
            }
        }
    }

    const int rbase = blockIdx.y * 128 + wr + (lane >> 4) * 4;
    const int cbase = blockIdx.x * 128 + wc + fr;
#pragma unroll
    for (int m = 0; m < 4; ++m) {
#pragma unroll
        for (int n = 0; n < 4; ++n) {
            const int col = cbase + n * 16;
#pragma unroll
            for (int r = 0; r < 4; ++r) {
                const int row = rbase + m * 16 + r;
                float v = acc[m][n][r];
                if (MODE == 0) {
                    out16[(size_t)row * out_stride + col] = __builtin_bit_cast(u16, (_Float16)v);
                } else if (MODE == 1) {
                    out16[(size_t)row * 1024 + col] = bf16b(v + addf[(size_t)row * 1024 + col]);
                } else if (MODE == 2) {
                    float u = v + bias[col];
                    u = 0.5f * u * (1.0f + erff(u * 0.70710678118654752f));
                    out16[(size_t)row * out_stride + col] = bf16b(u);
                } else {
                    out32[(size_t)row * 1024 + col] =
                        v + bias[col] + b2f(add16[(size_t)row * 1024 + col]);
                }
            }
        }
    }
}

// ---------------------------------------------------------------- MFMA scan
// ONE block, 256 threads (4 waves). 8 batches in MFMA cols (8 real + 8 pad).
// Wave w owns output rows [64w, 64w+64) as 4 tiles; A (f16) lives in registers.
// State (f16) double-buffered in LDS frag layout:
//   SB[p][kk*1024 + l*16 + j*2] = S[b = l&15][n = kk*32 + (l>>4)*8 + j]
// Epilogue halved via DPP ror:8 pad-lane recruiting: lane b<8 exports acc tiles
// 2,3 to lane b+8, each lane tanh's 8 values, results DPP'd back.
__global__ __launch_bounds__(256) void scan_mfma_kernel(
    const float* __restrict__ Am, const u16* __restrict__ xBh /*f16 [8][2048][256]*/,
    u16* __restrict__ sth /*f16 [8][2048][256]*/, float* __restrict__ fstate)
{
    __shared__ __align__(16) char SB[2][8192];
    const int tid = threadIdx.x;
    const int l = tid & 63, w = tid >> 6;
    const int b = l & 15, g = l >> 4;
    const int bc = b < 8 ? b : 7;
    const bool breal = (b < 8);

    // A fragments: af[nt][kk], lane holds A[64w+nt*16+b][kk*32 + g*8 + j]
    half8 af[4][8];
#pragma unroll
    for (int nt = 0; nt < 4; ++nt)
#pragma unroll
        for (int kk = 0; kk < 8; ++kk) {
            const float* ap = Am + (size_t)(64 * w + nt * 16 + b) * 256 + kk * 32 + g * 8;
            float4 f0 = *(const float4*)ap;
            float4 f1 = *(const float4*)(ap + 4);
            half8 h;
            h[0] = (_Float16)f0.x; h[1] = (_Float16)f0.y; h[2] = (_Float16)f0.z; h[3] = (_Float16)f0.w;
            h[4] = (_Float16)f1.x; h[5] = (_Float16)f1.y; h[6] = (_Float16)f1.z; h[7] = (_Float16)f1.w;
            af[nt][kk] = h;
        }

    {   // zero both state buffers (16 KiB)
        uint4 z = uint4{0u, 0u, 0u, 0u};
#pragma unroll
        for (int i = 0; i < 4; ++i)
            ((uint4*)SB)[tid + 256 * i] = z;
    }

    int n0[4], wb[4];
    const u16* xp[4];
    u16* sp[4];
#pragma unroll
    for (int nt = 0; nt < 4; ++nt) {
        int n = 64 * w + nt * 16 + g * 4;
        n0[nt] = n;
        wb[nt] = (n >> 5) * 1024 + (b + 16 * ((n & 31) >> 3)) * 16 + (n & 7) * 2;
        xp[nt] = xBh + (size_t)bc * 2048 * 256 + n;
        sp[nt] = sth + (size_t)bc * 2048 * 256 + n;
    }

    uint2 xa0, xa1, xa2, xa3, xb0, xb1, xb2, xb3;
    xa0 = *(const uint2*)(xp[0]);        xa1 = *(const uint2*)(xp[1]);
    xa2 = *(const uint2*)(xp[2]);        xa3 = *(const uint2*)(xp[3]);
    xb0 = *(const uint2*)(xp[0] + 256);  xb1 = *(const uint2*)(xp[1] + 256);
    xb2 = *(const uint2*)(xp[2] + 256);  xb3 = *(const uint2*)(xp[3] + 256);
#pragma unroll
    for (int nt = 0; nt < 4; ++nt) xp[nt] += 512;   // -> t=2
    __syncthreads();

#define UNPK(XC) f32x4{ (float)__builtin_bit_cast(h2_t, (XC).x)[0],            \
                        (float)__builtin_bit_cast(h2_t, (XC).x)[1],            \
                        (float)__builtin_bit_cast(h2_t, (XC).y)[0],            \
                        (float)__builtin_bit_cast(h2_t, (XC).y)[1] }

#define MM(KK)                                                                 \
    acc0 = __builtin_amdgcn_mfma_f32_16x16x32_f16(af[0][KK], __builtin_bit_cast(half8, s##KK), acc0, 0, 0, 0); \
    acc1 = __builtin_amdgcn_mfma_f32_16x16x32_f16(af[1][KK], __builtin_bit_cast(half8, s##KK), acc1, 0, 0, 0); \
    acc2 = __builtin_amdgcn_mfma_f32_16x16x32_f16(af[2][KK], __builtin_bit_cast(half8, s##KK), acc2, 0, 0, 0); \
    acc3 = __builtin_amdgcn_mfma_f32_16x16x32_f16(af[3][KK], __builtin_bit_cast(half8, s##KK), acc3, 0, 0, 0);

// One scan step. PR/PW: LDS buffer read/write. X0..X3: xb regs (consumed, then
// if PRELOAD, refilled with xb(t+2) from xp + XOFF). SOFF: st row offset.
// FS: final step -> write fstate.
#define STEP(PR, PW, X0, X1, X2, X3, PRELOAD, XOFF, SOFF, FS)                  \
    {                                                                          \
        const char* rb = &SB[PR][0] + l * 16;                                  \
        uint4 s0 = *(const uint4*)(rb + 0 * 1024);                             \
        uint4 s1 = *(const uint4*)(rb + 1 * 1024);                             \
        uint4 s2 = *(const uint4*)(rb + 2 * 1024);                             \
        uint4 s3 = *(const uint4*)(rb + 3 * 1024);                             \
        uint4 s4 = *(const uint4*)(rb + 4 * 1024);                             \
        uint4 s5 = *(const uint4*)(rb + 5 * 1024);                             \
        uint4 s6 = *(const uint4*)(rb + 6 * 1024);                             \
        uint4 s7 = *(const uint4*)(rb + 7 * 1024);                             \
        f32x4 acc0 = UNPK(X0), acc1 = UNPK(X1), acc2 = UNPK(X2), acc3 = UNPK(X3); \
        if (PRELOAD) {                                                         \
            X0 = *(const uint2*)(xp[0] + XOFF);                                \
            X1 = *(const uint2*)(xp[1] + XOFF);                                \
            X2 = *(const uint2*)(xp[2] + XOFF);                                \
            X3 = *(const uint2*)(xp[3] + XOFF);                                \
        }                                                                      \
        MM(0) MM(1) MM(2) MM(3) MM(4) MM(5) MM(6) MM(7)                        \
        /* export tiles 2,3 to pad partner (l ^ 8) */                          \
        f32x4 r2, r3;                                                          \
        _Pragma("unroll")                                                      \
        for (int i = 0; i < 4; ++i) { r2[i] = ror8_f32(acc2[i]); r3[i] = ror8_f32(acc3[i]); } \
        float h0 = tanh_e(breal ? acc0[0] : r2[0]);                            \
        float h1 = tanh_e(breal ? acc0[1] : r2[1]);                            \
        float h2 = tanh_e(breal ? acc0[2] : r2[2]);                            \
        float h3 = tanh_e(breal ? acc0[3] : r2[3]);                            \
        float h4 = tanh_e(breal ? acc1[0] : r3[0]);                            \
        float h5 = tanh_e(breal ? acc1[1] : r3[1]);                            \
        float h6 = tanh_e(breal ? acc1[2] : r3[2]);                            \
        float h7 = tanh_e(breal ? acc1[3] : r3[3]);                            \
        u32 pA0 = __builtin_bit_cast(u32, __builtin_amdgcn_cvt_pkrtz(h0, h1)); \
        u32 pA1 = __builtin_bit_cast(u32, __builtin_amdgcn_cvt_pkrtz(h2, h3)); \
        u32 pB0 = __builtin_bit_cast(u32, __builtin_amdgcn_cvt_pkrtz(h4, h5)); \
        u32 pB1 = __builtin_bit_cast(u32, __builtin_amdgcn_cvt_pkrtz(h6, h7)); \
        u32 rA0 = ror8_u32(pA0), rA1 = ror8_u32(pA1);                          \
        u32 rB0 = ror8_u32(pB0), rB1 = ror8_u32(pB1);                          \
        *(uint2*)(&SB[PW][0] + wb[0]) = uint2{pA0, pA1};                       \
        *(uint2*)(&SB[PW][0] + wb[1]) = uint2{pB0, pB1};                       \
        *(uint2*)(&SB[PW][0] + wb[2]) = uint2{rA0, rA1};                       \
        *(uint2*)(&SB[PW][0] + wb[3]) = uint2{rB0, rB1};                       \
        if (breal) {                                                           \
            *(uint2*)(sp[0] + SOFF) = uint2{pA0, pA1};                         \
            *(uint2*)(sp[1] + SOFF) = uint2{pB0, pB1};                         \
            *(uint2*)(sp[2] + SOFF) = uint2{rA0, rA1};                         \
            *(uint2*)(sp[3] + SOFF) = uint2{rB0, rB1};                         \
            if (FS) {                                                          \
                u32 pk4[4][2] = {{pA0, pA1}, {pB0, pB1}, {rA0, rA1}, {rB0, rB1}}; \
                _Pragma("unroll")                                              \
                for (int nt = 0; nt < 4; ++nt) {                               \
                    h2_t va = __builtin_bit_cast(h2_t, pk4[nt][0]);            \
                    h2_t vb = __builtin_bit_cast(h2_t, pk4[nt][1]);            \
                    *(float4*)(fstate + b * 256 + n0[nt]) =                    \
                        float4{(float)va[0], (float)va[1], (float)vb[0], (float)vb[1]}; \
                }                                                              \
            }                                                                  \
        }                                                                      \
        asm volatile("s_waitcnt lgkmcnt(0)\n\ts_barrier" ::: "memory");        \
    }

    // steps 0..2045 (1023 iterations x 2), prefetch always in range (<= 2047)
    for (int it = 0; it < 1023; ++it) {
        STEP(0, 1, xa0, xa1, xa2, xa3, true, 0,   0,   false)
        STEP(1, 0, xb0, xb1, xb2, xb3, true, 256, 256, false)
#pragma unroll
        for (int nt = 0; nt < 4; ++nt) { xp[nt] += 512; sp[nt] += 512; }
    }
    // peeled steps 2046, 2047 (no prefetch; final step writes fstate)
    STEP(0, 1, xa0, xa1, xa2, xa3, false, 0, 0,   false)
    STEP(1, 0, xb0, xb1, xb2, xb3, false, 0, 256, true)
#undef STEP
#undef MM
#undef UNPK
}

// ---------------------------------------------------------------- layernorm (row per block, bf16 in)
__global__ __launch_bounds__(256) void ln_kernel(
    const u16* __restrict__ pre /*bf16, stride 1024*/, const float* __restrict__ gam,
    const float* __restrict__ bet, u16* __restrict__ ybf)
{
    const int row = blockIdx.x, tid = threadIdx.x;
    const ushort4 pv = *(const ushort4*)(pre + (size_t)row * 1024 + tid * 4);
    float vx = b2f(pv.x), vy = b2f(pv.y), vz = b2f(pv.z), vw = b2f(pv.w);
    float sum = vx + vy + vz + vw;
    float sq  = vx * vx + vy * vy + vz * vz + vw * vw;
#pragma unroll
    for (int o = 32; o; o >>= 1) { sum += __shfl_xor(sum, o); sq += __shfl_xor(sq, o); }
    __shared__ float red[8];
    const int lane = tid & 63, wv = tid >> 6;
    if (!lane) { red[wv] = sum; red[4 + wv] = sq; }
    __syncthreads();
    sum = red[0] + red[1] + red[2] + red[3];
    sq  = red[4] + red[5] + red[6] + red[7];
    const float mu  = sum * (1.f / 1024.f);
    const float var = sq * (1.f / 1024.f) - mu * mu;
    const float rs  = rsqrtf(var + 1e-5f);
    const float4 g  = *(const float4*)(gam + tid * 4);
    const float4 be = *(const float4*)(bet + tid * 4);
    ushort4 ob;
    ob.x = bf16b((vx - mu) * rs * g.x + be.x);
    ob.y = bf16b((vy - mu) * rs * g.y + be.y);
    ob.z = bf16b((vz - mu) * rs * g.z + be.z);
    ob.w = bf16b((vw - mu) * rs * g.w + be.w);
    *(ushort4*)(ybf + (size_t)row * 1024 + tid * 4) = ob;
}

// ---------------------------------------------------------------- launch
extern "C" void kernel_launch(void* const* d_in, const int* in_sizes, int n_in,
                              void* d_out, int out_size, void* d_ws, size_t ws_size,
                              hipStream_t stream)
{
    const float* x    = (const float*)d_in[0];
    const float* A    = (const float*)d_in[1];
    const float* Bm   = (const float*)d_in[2];
    const float* C    = (const float*)d_in[3];
    const float* D    = (const float*)d_in[4];
    const float* ln_w = (const float*)d_in[5];
    const float* ln_b = (const float*)d_in[6];
    const float* W1   = (const float*)d_in[7];
    const float* b1   = (const float*)d_in[8];
    const float* W2   = (const float*)d_in[9];
    const float* b2   = (const float*)d_in[10];

    // workspace layout (total 135,790,592 B)
    char* ws = (char*)d_ws;
    u16* Bm_bf  = (u16*)(ws + 0);            //    524,288 B [256 x 1024] bf16
    u16* CD_bf  = (u16*)(ws + 524288);       //  2,621,440 B [1024 x 1280] = C(f16)|D(bf16)
    u16* W1b    = (u16*)(ws + 3145728);      //  8,388,608 B bf16
    u16* W2b    = (u16*)(ws + 11534336);     //  8,388,608 B bf16
    u16* xB_h   = (u16*)(ws + 19922944);     //  8,388,608 B [8][2048][256] f16
    u16* st_h   = (u16*)(ws + 28311552);     //  8,388,608 B [8][2048][256] f16
    u16* y_bf   = (u16*)(ws + 36700160);     // 33,554,432 B [16384 x 1024] bf16
    u16* pre_bf = (u16*)(ws + 70254592);     // 33,554,432 B [16384 x 1024] bf16
    u16* xh_bf  = (u16*)(ws + 103809024);    // 33,554,432 B shared: x_bf / h_bf

    float* out = (float*)d_out;              // [16384*1024] y, then [2048] final_state

    cvt_kernel<<<2048, 256, 0, stream>>>((const float4*)x,  (ushort4*)xh_bf, 4194304);
    cvt_kernel<<<256,  256, 0, stream>>>((const float4*)Bm, (ushort4*)Bm_bf, 65536);
    cvt_str_kernel<true ><<<256,  256, 0, stream>>>((const float4*)C, CD_bf, 64, 65536, 1280, 0);
    cvt_str_kernel<false><<<1024, 256, 0, stream>>>((const float4*)D, CD_bf, 256, 262144, 1280, 256);
    cvt_kernel<<<2048, 256, 0, stream>>>((const float4*)W1, (ushort4*)W1b, 1048576);
    cvt_kernel<<<2048, 256, 0, stream>>>((const float4*)W2, (ushort4*)W2b, 1048576);

    dim3 blk(256);
    // G1: xB = x @ Bm^T -> f16 [16384,256]
    gemm_bf16<0><<<dim3(2, 128), blk, 0, stream>>>(xh_bf, nullptr, Bm_bf, 1024, 16,
        nullptr, xB_h, nullptr, nullptr, nullptr, 256);
    // MFMA scan -> st_h (f16) + final_state (fp32 tail of d_out)
    scan_mfma_kernel<<<1, 256, 0, stream>>>(A, xB_h, st_h, out + 16777216);
    // G2: [st(f16) | x(bf16)] @ [C(f16) | D(bf16)]^T + x -> pre_bf (K=1280)
    gemm_bf16<1><<<dim3(8, 128), blk, 0, stream>>>(st_h, xh_bf, CD_bf, 1280, 20,
        nullptr, pre_bf, nullptr, x, nullptr, 1024);
    // LN
    ln_kernel<<<16384, 256, 0, stream>>>(pre_bf, ln_w, ln_b, y_bf);
    // FFN in 4 row-chunks of 4096 (h reuses xh_bf; x_bf dead after G2)
    for (int c = 0; c < 4; ++c) {
        const u16* yc = y_bf + (size_t)c * 4096 * 1024;
        float* oc = out + (size_t)c * 4096 * 1024;
        gemm_bf16<2><<<dim3(32, 32), blk, 0, stream>>>(yc, nullptr, W1b, 1024, 16,
            nullptr, xh_bf, b1, nullptr, nullptr, 4096);
        gemm_bf16<3><<<dim3(8, 32), blk, 0, stream>>>(xh_bf, nullptr, W2b, 4096, 64,
            oc, nullptr, b2, nullptr, yc, 1024);
    }
}

// Round 7
// 1997.661 us; speedup vs baseline: 1.3110x; 1.3047x over previous
//
#include <hip/hip_runtime.h>
#include <math.h>

typedef unsigned short u16;
typedef unsigned int u32;

using short8 = __attribute__((ext_vector_type(8))) short;
using f32x4  = __attribute__((ext_vector_type(4))) float;
typedef _Float16 h2_t __attribute__((ext_vector_type(2)));
using half8  = __attribute__((ext_vector_type(8))) _Float16;

typedef const __attribute__((address_space(1))) unsigned int* gas_ptr;
typedef __attribute__((address_space(3))) unsigned int* las_ptr;

__device__ __forceinline__ void load_lds16(const void* g, void* l) {
    __builtin_amdgcn_global_load_lds((gas_ptr)g, (las_ptr)l, 16, 0, 0);
}

__device__ __forceinline__ u16 bf16b(float f) {
    u32 u = __builtin_bit_cast(u32, f);
    u += 0x7fffu + ((u >> 16) & 1u);
    return (u16)(u >> 16);
}
__device__ __forceinline__ float b2f(u16 h) {
    u32 u = (u32)h << 16;
    return __builtin_bit_cast(float, u);
}

// tanh via exp2 + rcp: 3 VALU + 2 trans. Saturates exactly for |z| large.
__device__ __forceinline__ float tanh_e(float z) {
    float e = __builtin_amdgcn_exp2f(z * 2.885390081777927f);   // e^(2z)
    return 1.0f - 2.0f * __builtin_amdgcn_rcpf(e + 1.0f);
}

// pure-VALU cross-lane: rotate within each 16-lane row by 8 (involution: l <-> l^8)
__device__ __forceinline__ u32 ror8_u32(u32 v) {
    return (u32)__builtin_amdgcn_update_dpp(0, (int)v, 0x128, 0xF, 0xF, true);
}
__device__ __forceinline__ float ror8_f32(float v) {
    return __builtin_bit_cast(float,
        __builtin_amdgcn_update_dpp(0, __builtin_bit_cast(int, v), 0x128, 0xF, 0xF, true));
}

// ---------------------------------------------------------------- fp32 -> bf16 (contig)
__global__ void cvt_kernel(const float4* __restrict__ s, ushort4* __restrict__ d, int n4) {
    for (int i = blockIdx.x * blockDim.x + threadIdx.x; i < n4; i += gridDim.x * blockDim.x) {
        float4 v = s[i];
        ushort4 o;
        o.x = bf16b(v.x); o.y = bf16b(v.y); o.z = bf16b(v.z); o.w = bf16b(v.w);
        d[i] = o;
    }
}
// fp32 [R,K] -> bf16 or f16 into dst[r*stride + col0 + k]
template<bool F16>
__global__ void cvt_str_kernel(const float4* __restrict__ s, u16* __restrict__ d,
                               int K4, int n4, int stride, int col0) {
    for (int i = blockIdx.x * blockDim.x + threadIdx.x; i < n4; i += gridDim.x * blockDim.x) {
        float4 v = s[i];
        int r = i / K4, k4 = (i - r * K4) * 4;
        ushort4 o;
        if (F16) {
            o.x = __builtin_bit_cast(u16, (_Float16)v.x);
            o.y = __builtin_bit_cast(u16, (_Float16)v.y);
            o.z = __builtin_bit_cast(u16, (_Float16)v.z);
            o.w = __builtin_bit_cast(u16, (_Float16)v.w);
        } else {
            o.x = bf16b(v.x); o.y = bf16b(v.y); o.z = bf16b(v.z); o.w = bf16b(v.w);
        }
        *(ushort4*)(d + (size_t)r * stride + col0 + k4) = o;
    }
}

// ---------------------------------------------------------------- generic GEMM
// C[M,N] = A[M,K] * B^T, B is [N,K] row-major. 128x128 tile, BK=64, 256 thr.
template<int MODE>
__global__ __launch_bounds__(256) void gemm_bf16(
    const u16* __restrict__ Ab, const u16* __restrict__ Ab2, const u16* __restrict__ Bb,
    int K, int ktiles,
    float* __restrict__ out32, u16* __restrict__ out16,
    const float* __restrict__ bias, const float* __restrict__ addf,
    const u16* __restrict__ add16, int out_stride)
{
    __shared__ __align__(16) u16 Als[128 * 64];
    __shared__ __align__(16) u16 Bls[128 * 64];

    const int tid  = threadIdx.x;
    const int lane = tid & 63;
    const int w    = tid >> 6;
    const int wr   = (w >> 1) * 64;
    const int wc   = (w & 1) * 64;
    const int fr   = lane & 15;
    const int fkB  = (lane >> 4) * 16;

    const size_t rbB = (size_t)K * 2;
    const int arow = blockIdx.y * 128 + (tid >> 3);
    const char* Ag  = (const char*)Ab + (size_t)arow * ((MODE == 1) ? 512 : rbB) + (size_t)(tid & 7) * 16;
    const char* Ag2 = (MODE == 1) ? ((const char*)Ab2 + (size_t)arow * 2048 + (size_t)(tid & 7) * 16) : nullptr;
    const char* Bg  = (const char*)Bb + ((size_t)blockIdx.x * 128 + (tid >> 3)) * rbB + (size_t)(tid & 7) * 16;
    char* Ald = (char*)Als + tid * 16;
    char* Bld = (char*)Bls + tid * 16;

    f32x4 acc[4][4];
#pragma unroll
    for (int m = 0; m < 4; ++m)
#pragma unroll
        for (int n = 0; n < 4; ++n)
            acc[m][n] = f32x4{0.f, 0.f, 0.f, 0.f};

    for (int kt = 0; kt < ktiles; ++kt) {
        __syncthreads();
        const char* Asrc;
        size_t rbA;
        if (MODE == 1) {
            if (kt < 4) { Asrc = Ag  + (size_t)kt * 128;       rbA = 512;  }
            else        { Asrc = Ag2 + (size_t)(kt - 4) * 128; rbA = 2048; }
        } else {
            Asrc = Ag + (size_t)kt * 128; rbA = rbB;
        }
        const char* Bsrc = Bg + (size_t)kt * 128;
#pragma unroll
        for (int i = 0; i < 4; ++i) {
            load_lds16(Asrc + (size_t)(i * 32) * rbA, Ald + i * 4096);
            load_lds16(Bsrc + (size_t)(i * 32) * rbB, Bld + i * 4096);
        }
        __syncthreads();
        const bool f16t = (MODE == 1) && (kt < 4);
#pragma unroll
        for (int kk = 0; kk < 2; ++kk) {
            short8 af[4], bfr[4];
#pragma unroll
            for (int m = 0; m < 4; ++m)
                af[m] = *(const short8*)((const char*)Als + (wr + m * 16 + fr) * 128 + kk * 64 + fkB);
#pragma unroll
            for (int n = 0; n < 4; ++n)
                bfr[n] = *(const short8*)((const char*)Bls + (wc + n * 16 + fr) * 128 + kk * 64 + fkB);
            if (f16t) {
#pragma unroll
                for (int m = 0; m < 4; ++m)
#pragma unroll
                    for (int n = 0; n < 4; ++n)
                        acc[m][n] = __builtin_amdgcn_mfma_f32_16x16x32_f16(
                            __builtin_bit_cast(half8, af[m]), __builtin_bit_cast(half8, bfr[n]),
                            acc[m][n], 0, 0, 0);
            } else {
#pragma unroll
                for (int m = 0; m < 4; ++m)
#pragma unroll
                    for (int n = 0; n < 4; ++n)
                        acc[m][n] = __builtin_amdgcn_mfma_f32_16x16x32_bf16(af[m], bfr[n], acc[m][n], 0, 0, 0);
            }
        }
    }

    const int rbase = blockIdx.y * 128 + wr + (lane >> 4) * 4;
    const int cbase = blockIdx.x * 128 + wc + fr;
#pragma unroll
    for (int m = 0; m < 4; ++m) {
#pragma unroll
        for (int n = 0; n < 4; ++n) {
            const int col = cbase + n * 16;
#pragma unroll
            for (int r = 0; r < 4; ++r) {
                const int row = rbase + m * 16 + r;
                float v = acc[m][n][r];
                if (MODE == 0) {
                    out16[(size_t)row * out_stride + col] = __builtin_bit_cast(u16, (_Float16)v);
                } else if (MODE == 1) {
                    out16[(size_t)row * 1024 + col] = bf16b(v + addf[(size_t)row * 1024 + col]);
                } else if (MODE == 2) {
                    float u = v + bias[col];
                    u = 0.5f * u * (1.0f + erff(u * 0.70710678118654752f));
                    out16[(size_t)row * out_stride + col] = bf16b(u);
                } else {
                    out32[(size_t)row * 1024 + col] =
                        v + bias[col] + b2f(add16[(size_t)row * 1024 + col]);
                }
            }
        }
    }
}

// ---------------------------------------------------------------- MFMA scan (8 waves)
// ONE block, 512 threads (8 waves, 2 per SIMD). 8 batches in MFMA cols (+8 pad).
// Wave w owns output rows [32w, 32w+32) = 2 tiles of 16; A (f16) in registers
// (af[2][8] = 32 VGPR). State (f16) double-buffered in LDS frag layout:
//   SB[p][kk*1024 + l*16 + e*2] = S[n = kk*32 + (l>>4)*8 + e][col = l&15]
// Real data lives on cols 0-7 (low lanes). Epilogue: low lane exports acc1 to
// its pad partner (DPP ror:8); each lane tanh's 4 values (low: tile0, high:
// received tile1) and issues exactly one LDS b64 + one global b64 write.
__global__ __launch_bounds__(512) void scan_mfma_kernel(
    const float* __restrict__ Am, const u16* __restrict__ xBh /*f16 [8][2048][256]*/,
    u16* __restrict__ sth /*f16 [8][2048][256]*/, float* __restrict__ fstate)
{
    __shared__ __align__(16) char SB[2][8192];
    const int tid = threadIdx.x;
    const int l = tid & 63, w = tid >> 6;      // w in [0,8)
    const int b = l & 15, g = l >> 4;
    const int bt = b & 7;
    const bool low = (b < 8);

    // A fragments: af[nt][kk]: lane holds A[32w + nt*16 + b][kk*32 + g*8 + e]
    half8 af[2][8];
#pragma unroll
    for (int nt = 0; nt < 2; ++nt)
#pragma unroll
        for (int kk = 0; kk < 8; ++kk) {
            const float* ap = Am + (size_t)(32 * w + nt * 16 + b) * 256 + kk * 32 + g * 8;
            float4 f0 = *(const float4*)ap;
            float4 f1 = *(const float4*)(ap + 4);
            half8 h;
            h[0] = (_Float16)f0.x; h[1] = (_Float16)f0.y; h[2] = (_Float16)f0.z; h[3] = (_Float16)f0.w;
            h[4] = (_Float16)f1.x; h[5] = (_Float16)f1.y; h[6] = (_Float16)f1.z; h[7] = (_Float16)f1.w;
            af[nt][kk] = h;
        }

    {   // zero both state buffers (16 KiB = 1024 uint4 / 512 threads)
        uint4 z = uint4{0u, 0u, 0u, 0u};
        ((uint4*)SB)[tid] = z;
        ((uint4*)SB)[tid + 512] = z;
    }

    // lane's owned output rows: tile kh = (b>=8), rows n_own .. n_own+3, batch bt
    const int n_own = 32 * w + (low ? 0 : 16) + g * 4;
    const int wbyte = (n_own >> 5) * 1024 + (((n_own & 31) >> 3) * 16 + bt) * 16 + (n_own & 7) * 2;
    const u16* xq = xBh + (size_t)bt * 2048 * 256 + n_own;
    u16*       sq = sth + (size_t)bt * 2048 * 256 + n_own;

    uint2 xA = *(const uint2*)(xq);
    uint2 xB = *(const uint2*)(xq + 256);
    xq += 512;                                  // -> t = 2
    __syncthreads();

#define UNPK(XC) f32x4{ (float)__builtin_bit_cast(h2_t, (XC).x)[0],            \
                        (float)__builtin_bit_cast(h2_t, (XC).x)[1],            \
                        (float)__builtin_bit_cast(h2_t, (XC).y)[0],            \
                        (float)__builtin_bit_cast(h2_t, (XC).y)[1] }

#define MM(KK)                                                                 \
    acc0 = __builtin_amdgcn_mfma_f32_16x16x32_f16(af[0][KK], __builtin_bit_cast(half8, s##KK), acc0, 0, 0, 0); \
    acc1 = __builtin_amdgcn_mfma_f32_16x16x32_f16(af[1][KK], __builtin_bit_cast(half8, s##KK), acc1, 0, 0, 0);

// One scan step. PR/PW: LDS read/write buffer. XC: this step's xb (consumed;
// refilled from xq+XOFF if PRELOAD). SOFF: state-row offset. FS: write fstate.
#define STEP(PR, PW, XC, PRELOAD, XOFF, SOFF, FS)                              \
    {                                                                          \
        const char* rb = &SB[PR][0] + l * 16;                                  \
        uint4 s0 = *(const uint4*)(rb + 0 * 1024);                             \
        uint4 s1 = *(const uint4*)(rb + 1 * 1024);                             \
        uint4 s2 = *(const uint4*)(rb + 2 * 1024);                             \
        uint4 s3 = *(const uint4*)(rb + 3 * 1024);                             \
        uint4 s4 = *(const uint4*)(rb + 4 * 1024);                             \
        uint4 s5 = *(const uint4*)(rb + 5 * 1024);                             \
        uint4 s6 = *(const uint4*)(rb + 6 * 1024);                             \
        uint4 s7 = *(const uint4*)(rb + 7 * 1024);                             \
        /* acc0 (tile0): own xb is correct on low lanes (pad cols: don't-care) */ \
        f32x4 acc0 = UNPK(XC);                                                 \
        uint2 xpart;                                                           \
        xpart.x = ror8_u32(XC.x);                                              \
        xpart.y = ror8_u32(XC.y);                                              \
        /* acc1 (tile1): low lane gets partner's (tile1) xb via DPP */         \
        f32x4 acc1 = UNPK(xpart);                                              \
        if (PRELOAD) { XC = *(const uint2*)(xq + XOFF); }                      \
        MM(0) MM(1) MM(2) MM(3) MM(4) MM(5) MM(6) MM(7)                        \
        /* export tile1 results to pad partner */                              \
        f32x4 r1;                                                              \
        _Pragma("unroll")                                                      \
        for (int i = 0; i < 4; ++i) r1[i] = ror8_f32(acc1[i]);                 \
        float t0 = low ? acc0[0] : r1[0];                                      \
        float t1 = low ? acc0[1] : r1[1];                                      \
        float t2 = low ? acc0[2] : r1[2];                                      \
        float t3 = low ? acc0[3] : r1[3];                                      \
        float h0 = tanh_e(t0);                                                 \
        float h1 = tanh_e(t1);                                                 \
        float h2 = tanh_e(t2);                                                 \
        float h3 = tanh_e(t3);                                                 \
        u32 p0 = __builtin_bit_cast(u32, __builtin_amdgcn_cvt_pkrtz(h0, h1));  \
        u32 p1 = __builtin_bit_cast(u32, __builtin_amdgcn_cvt_pkrtz(h2, h3));  \
        *(uint2*)(&SB[PW][0] + wbyte) = uint2{p0, p1};                         \
        *(uint2*)(sq + SOFF) = uint2{p0, p1};                                  \
        if (FS) *(float4*)(fstate + bt * 256 + n_own) = float4{h0, h1, h2, h3}; \
        asm volatile("s_waitcnt lgkmcnt(0)\n\ts_barrier" ::: "memory");        \
    }

    // steps 0..2045 (1023 iterations x 2); prefetch targets t+2 <= 2047
    for (int it = 0; it < 1023; ++it) {
        STEP(0, 1, xA, true, 0,   0,   false)
        STEP(1, 0, xB, true, 256, 256, false)
        xq += 512; sq += 512;
    }
    // peeled steps 2046, 2047 (no prefetch; final step writes fstate)
    STEP(0, 1, xA, false, 0, 0,   false)
    STEP(1, 0, xB, false, 0, 256, true)
#undef STEP
#undef MM
#undef UNPK
}

// ---------------------------------------------------------------- layernorm (row per block, bf16 in)
__global__ __launch_bounds__(256) void ln_kernel(
    const u16* __restrict__ pre /*bf16, stride 1024*/, const float* __restrict__ gam,
    const float* __restrict__ bet, u16* __restrict__ ybf)
{
    const int row = blockIdx.x, tid = threadIdx.x;
    const ushort4 pv = *(const ushort4*)(pre + (size_t)row * 1024 + tid * 4);
    float vx = b2f(pv.x), vy = b2f(pv.y), vz = b2f(pv.z), vw = b2f(pv.w);
    float sum = vx + vy + vz + vw;
    float sq  = vx * vx + vy * vy + vz * vz + vw * vw;
#pragma unroll
    for (int o = 32; o; o >>= 1) { sum += __shfl_xor(sum, o); sq += __shfl_xor(sq, o); }
    __shared__ float red[8];
    const int lane = tid & 63, wv = tid >> 6;
    if (!lane) { red[wv] = sum; red[4 + wv] = sq; }
    __syncthreads();
    sum = red[0] + red[1] + red[2] + red[3];
    sq  = red[4] + red[5] + red[6] + red[7];
    const float mu  = sum * (1.f / 1024.f);
    const float var = sq * (1.f / 1024.f) - mu * mu;
    const float rs  = rsqrtf(var + 1e-5f);
    const float4 g  = *(const float4*)(gam + tid * 4);
    const float4 be = *(const float4*)(bet + tid * 4);
    ushort4 ob;
    ob.x = bf16b((vx - mu) * rs * g.x + be.x);
    ob.y = bf16b((vy - mu) * rs * g.y + be.y);
    ob.z = bf16b((vz - mu) * rs * g.z + be.z);
    ob.w = bf16b((vw - mu) * rs * g.w + be.w);
    *(ushort4*)(ybf + (size_t)row * 1024 + tid * 4) = ob;
}

// ---------------------------------------------------------------- launch
extern "C" void kernel_launch(void* const* d_in, const int* in_sizes, int n_in,
                              void* d_out, int out_size, void* d_ws, size_t ws_size,
                              hipStream_t stream)
{
    const float* x    = (const float*)d_in[0];
    const float* A    = (const float*)d_in[1];
    const float* Bm   = (const float*)d_in[2];
    const float* C    = (const float*)d_in[3];
    const float* D    = (const float*)d_in[4];
    const float* ln_w = (const float*)d_in[5];
    const float* ln_b = (const float*)d_in[6];
    const float* W1   = (const float*)d_in[7];
    const float* b1   = (const float*)d_in[8];
    const float* W2   = (const float*)d_in[9];
    const float* b2   = (const float*)d_in[10];

    // workspace layout (total 135,790,592 B)
    char* ws = (char*)d_ws;
    u16* Bm_bf  = (u16*)(ws + 0);            //    524,288 B [256 x 1024] bf16
    u16* CD_bf  = (u16*)(ws + 524288);       //  2,621,440 B [1024 x 1280] = C(f16)|D(bf16)
    u16* W1b    = (u16*)(ws + 3145728);      //  8,388,608 B bf16
    u16* W2b    = (u16*)(ws + 11534336);     //  8,388,608 B bf16
    u16* xB_h   = (u16*)(ws + 19922944);     //  8,388,608 B [8][2048][256] f16
    u16* st_h   = (u16*)(ws + 28311552);     //  8,388,608 B [8][2048][256] f16
    u16* y_bf   = (u16*)(ws + 36700160);     // 33,554,432 B [16384 x 1024] bf16
    u16* pre_bf = (u16*)(ws + 70254592);     // 33,554,432 B [16384 x 1024] bf16
    u16* xh_bf  = (u16*)(ws + 103809024);    // 33,554,432 B shared: x_bf / h_bf

    float* out = (float*)d_out;              // [16384*1024] y, then [2048] final_state

    cvt_kernel<<<2048, 256, 0, stream>>>((const float4*)x,  (ushort4*)xh_bf, 4194304);
    cvt_kernel<<<256,  256, 0, stream>>>((const float4*)Bm, (ushort4*)Bm_bf, 65536);
    cvt_str_kernel<true ><<<256,  256, 0, stream>>>((const float4*)C, CD_bf, 64, 65536, 1280, 0);
    cvt_str_kernel<false><<<1024, 256, 0, stream>>>((const float4*)D, CD_bf, 256, 262144, 1280, 256);
    cvt_kernel<<<2048, 256, 0, stream>>>((const float4*)W1, (ushort4*)W1b, 1048576);
    cvt_kernel<<<2048, 256, 0, stream>>>((const float4*)W2, (ushort4*)W2b, 1048576);

    dim3 blk(256);
    // G1: xB = x @ Bm^T -> f16 [16384,256]
    gemm_bf16<0><<<dim3(2, 128), blk, 0, stream>>>(xh_bf, nullptr, Bm_bf, 1024, 16,
        nullptr, xB_h, nullptr, nullptr, nullptr, 256);
    // MFMA scan -> st_h (f16) + final_state (fp32 tail of d_out)
    scan_mfma_kernel<<<1, 512, 0, stream>>>(A, xB_h, st_h, out + 16777216);
    // G2: [st(f16) | x(bf16)] @ [C(f16) | D(bf16)]^T + x -> pre_bf (K=1280)
    gemm_bf16<1><<<dim3(8, 128), blk, 0, stream>>>(st_h, xh_bf, CD_bf, 1280, 20,
        nullptr, pre_bf, nullptr, x, nullptr, 1024);
    // LN
    ln_kernel<<<16384, 256, 0, stream>>>(pre_bf, ln_w, ln_b, y_bf);
    // FFN in 4 row-chunks of 4096 (h reuses xh_bf; x_bf dead after G2)
    for (int c = 0; c < 4; ++c) {
        const u16* yc = y_bf + (size_t)c * 4096 * 1024;
        float* oc = out + (size_t)c * 4096 * 1024;
        gemm_bf16<2><<<dim3(32, 32), blk, 0, stream>>>(yc, nullptr, W1b, 1024, 16,
            nullptr, xh_bf, b1, nullptr, nullptr, 4096);
        gemm_bf16<3><<<dim3(8, 32), blk, 0, stream>>>(xh_bf, nullptr, W2b, 4096, 64,
            oc, nullptr, b2, nullptr, yc, 1024);
    }
}